// Round 1
// baseline (985.470 us; speedup 1.0000x reference)
//
#include <hip/hip_runtime.h>
#include <hip/hip_bf16.h>

// MLA forward, MI355X. B=2, S=2048, DIM=2048, H=16, QK_HD=192 (128 nope + 64 rope), V_HD=128.
// Strategy: one-time fp32->bf16 conversion (weights transposed to [N][K]),
// all GEMMs via bf16 MFMA 16x16x32 (128x128 tile, 4 waves, fp32 accum),
// flash-style attention (64 q-rows/block, online softmax), fp32 epilogue on final GEMM.

typedef __attribute__((ext_vector_type(8))) short short8;
typedef __attribute__((ext_vector_type(4))) float f32x4;

static __device__ __forceinline__ unsigned short bf16_bits(float f) {
  __hip_bfloat16 h = __float2bfloat16(f);
  return __builtin_bit_cast(unsigned short, h);
}
static __device__ __forceinline__ float bf16_to_f(unsigned short u) {
  unsigned int v = (unsigned int)u << 16;
  return __builtin_bit_cast(float, v);
}

// ---------------- conversion kernels ----------------

__global__ void k_f32_to_bf16(const float* __restrict__ in, unsigned short* __restrict__ out, int n4) {
  int i = blockIdx.x * 256 + threadIdx.x;
  if (i >= n4) return;
  float4 v = reinterpret_cast<const float4*>(in)[i];
  ushort4 o;
  o.x = bf16_bits(v.x); o.y = bf16_bits(v.y); o.z = bf16_bits(v.z); o.w = bf16_bits(v.w);
  reinterpret_cast<ushort4*>(out)[i] = o;
}

// W[K][N] fp32 -> Wt[N][K] bf16 (LDS-tiled transpose)
__global__ void k_transpose_bf16(const float* __restrict__ W, unsigned short* __restrict__ Wt,
                                 int K, int N) {
  __shared__ float tile[32][33];
  int k0 = blockIdx.x * 32, n0 = blockIdx.y * 32;
  int tx = threadIdx.x & 31, ty = threadIdx.x >> 5;  // ty 0..7
#pragma unroll
  for (int i = 0; i < 32; i += 8) {
    int k = k0 + ty + i, n = n0 + tx;
    tile[ty + i][tx] = (k < K && n < N) ? W[(size_t)k * N + n] : 0.f;
  }
  __syncthreads();
#pragma unroll
  for (int i = 0; i < 32; i += 8) {
    int n = n0 + ty + i, k = k0 + tx;
    if (n < N && k < K) Wt[(size_t)n * K + k] = bf16_bits(tile[tx][ty + i]);
  }
}

// ---------------- RoPE ----------------

// cs[s][i] = (cos, sin) of s * theta^(-2i/64), s in [0,2048), i in [0,32)
__global__ void k_rope_table(float2* __restrict__ cs) {
  int idx = blockIdx.x * 256 + threadIdx.x;  // 2048*32 total
  int s = idx >> 5, i = idx & 31;
  float inv = powf(1.0e6f, -(float)(2 * i) / 64.0f);
  float a = (float)s * inv;
  cs[idx] = make_float2(cosf(a), sinf(a));
}

// q buffer (BS, 16, 192) bf16; rotate dims [128,192) in place. one thread per pair.
__global__ void k_rope_q(unsigned short* __restrict__ q, const float2* __restrict__ cs) {
  int idx = blockIdx.x * 256 + threadIdx.x;  // BS*16*32
  int i = idx & 31;
  int h = (idx >> 5) & 15;
  int bs = idx >> 9;
  int s = bs & 2047;
  size_t base = (size_t)bs * 3072 + h * 192 + 128 + 2 * i;
  float xr = bf16_to_f(q[base]);
  float xi = bf16_to_f(q[base + 1]);
  float2 c = cs[(s << 5) + i];
  q[base]     = bf16_bits(xr * c.x - xi * c.y);
  q[base + 1] = bf16_bits(xr * c.y + xi * c.x);
}

// ckv buffer (BS, 576) bf16; rotate dims [512,576) in place.
__global__ void k_rope_k(unsigned short* __restrict__ ckv, const float2* __restrict__ cs) {
  int idx = blockIdx.x * 256 + threadIdx.x;  // BS*32
  int i = idx & 31;
  int bs = idx >> 5;
  int s = bs & 2047;
  size_t base = (size_t)bs * 576 + 512 + 2 * i;
  float xr = bf16_to_f(ckv[base]);
  float xi = bf16_to_f(ckv[base + 1]);
  float2 c = cs[(s << 5) + i];
  ckv[base]     = bf16_bits(xr * c.x - xi * c.y);
  ckv[base + 1] = bf16_bits(xr * c.y + xi * c.x);
}

// ---------------- GEMM: C[M][N] = A[M][K](lda) @ Wt[N][K]^T + bias ----------------
// 128x128 tile, BK=64, 256 threads (4 waves 2x2), each wave 64x64 via 4x4 16x16x32 MFMA frags.

template <typename OutT>
__global__ __launch_bounds__(256, 2) void k_gemm(const unsigned short* __restrict__ A, int lda,
                                                 const unsigned short* __restrict__ Wt,
                                                 const float* __restrict__ bias,
                                                 OutT* __restrict__ C, int M, int N, int K) {
  __shared__ unsigned short lA[128][72];  // +8 pad -> 2-way-free bank pattern
  __shared__ unsigned short lB[128][72];
  int m0 = blockIdx.x * 128, n0 = blockIdx.y * 128;
  int t = threadIdx.x;
  int lane = t & 63, wid = t >> 6;
  int g = lane >> 4, col = lane & 15;
  int wr = wid >> 1, wc = wid & 1;
  int trow = t >> 3, tcol = (t & 7) * 8;
  f32x4 acc[4][4] = {};

  for (int kt = 0; kt < K; kt += 64) {
#pragma unroll
    for (int rr = 0; rr < 4; ++rr) {
      int row = trow + 32 * rr;
      *reinterpret_cast<short8*>(&lA[row][tcol]) =
          *reinterpret_cast<const short8*>(&A[(size_t)(m0 + row) * lda + kt + tcol]);
      short8 bv = {};
      if (n0 + row < N)
        bv = *reinterpret_cast<const short8*>(&Wt[(size_t)(n0 + row) * K + kt + tcol]);
      *reinterpret_cast<short8*>(&lB[row][tcol]) = bv;
    }
    __syncthreads();
#pragma unroll
    for (int kk = 0; kk < 64; kk += 32) {
      short8 a[4], b[4];
#pragma unroll
      for (int mf = 0; mf < 4; ++mf)
        a[mf] = *reinterpret_cast<const short8*>(&lA[64 * wr + 16 * mf + col][kk + 8 * g]);
#pragma unroll
      for (int nf = 0; nf < 4; ++nf)
        b[nf] = *reinterpret_cast<const short8*>(&lB[64 * wc + 16 * nf + col][kk + 8 * g]);
#pragma unroll
      for (int mf = 0; mf < 4; ++mf)
#pragma unroll
        for (int nf = 0; nf < 4; ++nf)
          acc[mf][nf] = __builtin_amdgcn_mfma_f32_16x16x32_bf16(a[mf], b[nf], acc[mf][nf], 0, 0, 0);
    }
    __syncthreads();
  }

#pragma unroll
  for (int mf = 0; mf < 4; ++mf) {
#pragma unroll
    for (int nf = 0; nf < 4; ++nf) {
      int n = n0 + 64 * wc + 16 * nf + col;
      if (n >= N) continue;
      float bv = bias[n];
#pragma unroll
      for (int r = 0; r < 4; ++r) {
        int m = m0 + 64 * wr + 16 * mf + 4 * g + r;
        float v = acc[mf][nf][r] + bv;
        if constexpr (sizeof(OutT) == 4)
          C[(size_t)m * N + n] = v;
        else
          C[(size_t)m * N + n] = bf16_bits(v);
      }
    }
  }
}

// ---------------- flash attention ----------------
// grid = B*H*(S/64); 256 threads = 4 waves, wave w owns q-rows [q0+16w, q0+16w+16).
// K-tile 64x192 and V^T 128x64 staged in LDS; online softmax per wave (16-lane shfl reduce).

__global__ __launch_bounds__(256, 2) void k_attn(const unsigned short* __restrict__ q,
                                                 const unsigned short* __restrict__ ckv,
                                                 const unsigned short* __restrict__ kv,
                                                 unsigned short* __restrict__ out) {
  __shared__ unsigned short lK[64][200];    // 64 kv-rows x 192 dims (+8 pad)
  __shared__ unsigned short lV[128][72];    // V^T: 128 dv x 64 kv (+8 pad)
  __shared__ unsigned short lP[4][16][72];  // per-wave P 16x64 (+8 pad)
  int bx = blockIdx.x;
  int qt = bx & 31, h = (bx >> 5) & 15, b = bx >> 9;
  int t = threadIdx.x, lane = t & 63, w = t >> 6;
  int g = lane >> 4, col = lane & 15;
  int q0 = qt * 64;
  const float scale = 0.08838834764831845f;  // 1/sqrt(128)

  short8 qf[6];
  {
    int srow = b * 2048 + q0 + 16 * w + col;
    size_t base = ((size_t)srow * 16 + h) * 192 + 8 * g;
#pragma unroll
    for (int j = 0; j < 6; ++j)
      qf[j] = *reinterpret_cast<const short8*>(&q[base + 32 * j]);
  }

  f32x4 o[8] = {};
  float mrow[4] = {-1e30f, -1e30f, -1e30f, -1e30f};
  float lrow[4] = {0.f, 0.f, 0.f, 0.f};

  for (int k0 = 0; k0 < 2048; k0 += 64) {
    __syncthreads();  // prior PV reads done before overwrite
    // stage K: 64 rows x 24 chunks of 8 bf16 (nope from kv, rope from ckv)
#pragma unroll
    for (int it = 0; it < 6; ++it) {
      int c = t + 256 * it;
      int row = c / 24, cc = c % 24;
      int s = b * 2048 + k0 + row;
      const unsigned short* src;
      if (cc < 16) src = &kv[((size_t)s * 16 + h) * 256 + cc * 8];
      else         src = &ckv[(size_t)s * 576 + 512 + (cc - 16) * 8];
      *reinterpret_cast<short8*>(&lK[row][cc * 8]) = *reinterpret_cast<const short8*>(src);
    }
    // stage V transposed: coalesced 16B read, scattered u16 writes
#pragma unroll
    for (int it = 0; it < 4; ++it) {
      int c = t + 256 * it;
      int row = c >> 4, dv0 = (c & 15) * 8;
      int s = b * 2048 + k0 + row;
      short8 v = *reinterpret_cast<const short8*>(&kv[((size_t)s * 16 + h) * 256 + 128 + dv0]);
#pragma unroll
      for (int j = 0; j < 8; ++j) lV[dv0 + j][row] = (unsigned short)v[j];
    }
    __syncthreads();

    // S = Q K^T for this wave's 16 rows x 64 cols
    f32x4 sf[4];
#pragma unroll
    for (int c = 0; c < 4; ++c) {
      f32x4 acc = {};
#pragma unroll
      for (int j = 0; j < 6; ++j) {
        short8 bfr = *reinterpret_cast<const short8*>(&lK[16 * c + col][32 * j + 8 * g]);
        acc = __builtin_amdgcn_mfma_f32_16x16x32_bf16(qf[j], bfr, acc, 0, 0, 0);
      }
      sf[c] = acc;
    }

    // online softmax; row r of this lane = q0+16w+4g+r, 16 k-cols per lane-group
#pragma unroll
    for (int r = 0; r < 4; ++r) {
      float tm = -1e30f;
#pragma unroll
      for (int c = 0; c < 4; ++c) { sf[c][r] *= scale; tm = fmaxf(tm, sf[c][r]); }
#pragma unroll
      for (int off = 8; off; off >>= 1) tm = fmaxf(tm, __shfl_xor(tm, off, 64));
      float mn = fmaxf(mrow[r], tm);
      float rs = __expf(mrow[r] - mn);
      mrow[r] = mn;
      float ps = 0.f;
#pragma unroll
      for (int c = 0; c < 4; ++c) { float p = __expf(sf[c][r] - mn); sf[c][r] = p; ps += p; }
#pragma unroll
      for (int off = 8; off; off >>= 1) ps += __shfl_xor(ps, off, 64);
      lrow[r] = lrow[r] * rs + ps;
#pragma unroll
      for (int n = 0; n < 8; ++n) o[n][r] *= rs;
    }

    // P -> LDS (bf16), then PV
#pragma unroll
    for (int c = 0; c < 4; ++c)
#pragma unroll
      for (int r = 0; r < 4; ++r)
        lP[w][4 * g + r][16 * c + col] = bf16_bits(sf[c][r]);
    __syncthreads();  // also orders lP write->read
#pragma unroll
    for (int kk = 0; kk < 64; kk += 32) {
      short8 pa = *reinterpret_cast<const short8*>(&lP[w][col][kk + 8 * g]);
#pragma unroll
      for (int n = 0; n < 8; ++n) {
        short8 bv = *reinterpret_cast<const short8*>(&lV[16 * n + col][kk + 8 * g]);
        o[n] = __builtin_amdgcn_mfma_f32_16x16x32_bf16(pa, bv, o[n], 0, 0, 0);
      }
    }
  }

  // epilogue: normalize, write (B,S,H*128) bf16
#pragma unroll
  for (int r = 0; r < 4; ++r) {
    float inv = 1.0f / lrow[r];
    int srow = b * 2048 + q0 + 16 * w + 4 * g + r;
    size_t base = (size_t)srow * 2048 + h * 128;
#pragma unroll
    for (int n = 0; n < 8; ++n)
      out[base + 16 * n + col] = bf16_bits(o[n][r] * inv);
  }
}

// ---------------- host ----------------

extern "C" void kernel_launch(void* const* d_in, const int* in_sizes, int n_in,
                              void* d_out, int out_size, void* d_ws, size_t ws_size,
                              hipStream_t stream) {
  const float* x       = (const float*)d_in[0];
  const float* wq_a_w  = (const float*)d_in[1];
  const float* wq_a_b  = (const float*)d_in[2];
  const float* wq_b_w  = (const float*)d_in[3];
  const float* wq_b_b  = (const float*)d_in[4];
  const float* wkv_a_w = (const float*)d_in[5];
  const float* wkv_a_b = (const float*)d_in[6];
  const float* wkv_b_w = (const float*)d_in[7];
  const float* wkv_b_b = (const float*)d_in[8];
  const float* wo_w    = (const float*)d_in[9];
  const float* wo_b    = (const float*)d_in[10];
  float* out = (float*)d_out;

  const int BS = 4096;  // B*S = 2*2048
  char* p = (char*)d_ws;
  auto alloc = [&](size_t bytes) { char* r = p; p += (bytes + 255) & ~(size_t)255; return r; };
  unsigned short* xb    = (unsigned short*)alloc((size_t)BS * 2048 * 2);
  unsigned short* wqat  = (unsigned short*)alloc((size_t)512 * 2048 * 2);
  unsigned short* wqbt  = (unsigned short*)alloc((size_t)3072 * 512 * 2);
  unsigned short* wkvat = (unsigned short*)alloc((size_t)576 * 2048 * 2);
  unsigned short* wkvbt = (unsigned short*)alloc((size_t)4096 * 512 * 2);
  unsigned short* wot   = (unsigned short*)alloc((size_t)2048 * 2048 * 2);
  unsigned short* qa    = (unsigned short*)alloc((size_t)BS * 512 * 2);
  unsigned short* qbuf  = (unsigned short*)alloc((size_t)BS * 3072 * 2);
  unsigned short* ckv   = (unsigned short*)alloc((size_t)BS * 576 * 2);
  unsigned short* kvbuf = (unsigned short*)alloc((size_t)BS * 4096 * 2);
  unsigned short* attno = (unsigned short*)alloc((size_t)BS * 2048 * 2);
  float2* cs            = (float2*)alloc((size_t)2048 * 32 * sizeof(float2));
  // total ws use ~122 MB

  k_f32_to_bf16<<<BS * 2048 / 4 / 256, 256, 0, stream>>>(x, xb, BS * 2048 / 4);
  k_transpose_bf16<<<dim3(2048 / 32, 512 / 32), 256, 0, stream>>>(wq_a_w, wqat, 2048, 512);
  k_transpose_bf16<<<dim3(512 / 32, 3072 / 32), 256, 0, stream>>>(wq_b_w, wqbt, 512, 3072);
  k_transpose_bf16<<<dim3(2048 / 32, 576 / 32), 256, 0, stream>>>(wkv_a_w, wkvat, 2048, 576);
  k_transpose_bf16<<<dim3(512 / 32, 4096 / 32), 256, 0, stream>>>(wkv_b_w, wkvbt, 512, 4096);
  k_transpose_bf16<<<dim3(2048 / 32, 2048 / 32), 256, 0, stream>>>(wo_w, wot, 2048, 2048);
  k_rope_table<<<2048 * 32 / 256, 256, 0, stream>>>(cs);

  // GEMM1: q_a = x @ wq_a + b
  k_gemm<unsigned short><<<dim3(BS / 128, 512 / 128), 256, 0, stream>>>(
      xb, 2048, wqat, wq_a_b, qa, BS, 512, 2048);
  // GEMM2: q = q_a @ wq_b + b
  k_gemm<unsigned short><<<dim3(BS / 128, 3072 / 128), 256, 0, stream>>>(
      qa, 512, wqbt, wq_b_b, qbuf, BS, 3072, 512);
  // GEMM3: ckv = x @ wkv_a + b
  k_gemm<unsigned short><<<dim3(BS / 128, (576 + 127) / 128), 256, 0, stream>>>(
      xb, 2048, wkvat, wkv_a_b, ckv, BS, 576, 2048);
  // RoPE in place
  k_rope_q<<<BS * 16 * 32 / 256, 256, 0, stream>>>(qbuf, cs);
  k_rope_k<<<BS * 32 / 256, 256, 0, stream>>>(ckv, cs);
  // GEMM4: kv = compressed_kv @ wkv_b + b   (reads first 512 cols of ckv)
  k_gemm<unsigned short><<<dim3(BS / 128, 4096 / 128), 256, 0, stream>>>(
      ckv, 576, wkvbt, wkv_b_b, kvbuf, BS, 4096, 512);
  // attention
  k_attn<<<2 * 16 * 32, 256, 0, stream>>>(qbuf, ckv, kvbuf, attno);
  // GEMM5: final projection, fp32 out
  k_gemm<float><<<dim3(BS / 128, 2048 / 128), 256, 0, stream>>>(
      attno, 2048, wot, wo_b, out, BS, 2048, 2048);
}

// Round 3
// 511.230 us; speedup vs baseline: 1.9276x; 1.9276x over previous
//
#include <hip/hip_runtime.h>
#include <hip/hip_bf16.h>

// MLA forward, MI355X. B=2, S=2048, DIM=2048, H=16, QK_HD=192 (128 nope + 64 rope), V_HD=128.
// R2: (a) attention: 8 waves/block, q-tile 128, XOR-swizzled V^T staging;
//     (b) GEMM: global_load_lds width=16 staging, linear LDS + inverse-swizzled
//         global source + swizzled ds_read (rule #21 / m201 pattern).

typedef __attribute__((ext_vector_type(8))) short short8;
typedef __attribute__((ext_vector_type(4))) float f32x4;

#define GLOAD_LDS16(gp, lp)                                                      \
  __builtin_amdgcn_global_load_lds((const __attribute__((address_space(1))) void*)(gp), \
                                   (__attribute__((address_space(3))) void*)(lp), 16, 0, 0)

static __device__ __forceinline__ unsigned short bf16_bits(float f) {
  __hip_bfloat16 h = __float2bfloat16(f);
  return __builtin_bit_cast(unsigned short, h);
}
static __device__ __forceinline__ float bf16_to_f(unsigned short u) {
  unsigned int v = (unsigned int)u << 16;
  return __builtin_bit_cast(float, v);
}

// ---------------- conversion kernels ----------------

__global__ void k_f32_to_bf16(const float* __restrict__ in, unsigned short* __restrict__ out, int n4) {
  int i = blockIdx.x * 256 + threadIdx.x;
  if (i >= n4) return;
  float4 v = reinterpret_cast<const float4*>(in)[i];
  ushort4 o;
  o.x = bf16_bits(v.x); o.y = bf16_bits(v.y); o.z = bf16_bits(v.z); o.w = bf16_bits(v.w);
  reinterpret_cast<ushort4*>(out)[i] = o;
}

// W[K][N] fp32 -> Wt[N][K] bf16 (LDS-tiled transpose)
__global__ void k_transpose_bf16(const float* __restrict__ W, unsigned short* __restrict__ Wt,
                                 int K, int N) {
  __shared__ float tile[32][33];
  int k0 = blockIdx.x * 32, n0 = blockIdx.y * 32;
  int tx = threadIdx.x & 31, ty = threadIdx.x >> 5;  // ty 0..7
#pragma unroll
  for (int i = 0; i < 32; i += 8) {
    int k = k0 + ty + i, n = n0 + tx;
    tile[ty + i][tx] = (k < K && n < N) ? W[(size_t)k * N + n] : 0.f;
  }
  __syncthreads();
#pragma unroll
  for (int i = 0; i < 32; i += 8) {
    int n = n0 + ty + i, k = k0 + tx;
    if (n < N && k < K) Wt[(size_t)n * K + k] = bf16_bits(tile[tx][ty + i]);
  }
}

// ---------------- RoPE ----------------

__global__ void k_rope_table(float2* __restrict__ cs) {
  int idx = blockIdx.x * 256 + threadIdx.x;  // 2048*32 total
  int s = idx >> 5, i = idx & 31;
  float inv = powf(1.0e6f, -(float)(2 * i) / 64.0f);
  float a = (float)s * inv;
  cs[idx] = make_float2(cosf(a), sinf(a));
}

__global__ void k_rope_q(unsigned short* __restrict__ q, const float2* __restrict__ cs) {
  int idx = blockIdx.x * 256 + threadIdx.x;  // BS*16*32
  int i = idx & 31;
  int h = (idx >> 5) & 15;
  int bs = idx >> 9;
  int s = bs & 2047;
  size_t base = (size_t)bs * 3072 + h * 192 + 128 + 2 * i;
  float xr = bf16_to_f(q[base]);
  float xi = bf16_to_f(q[base + 1]);
  float2 c = cs[(s << 5) + i];
  q[base]     = bf16_bits(xr * c.x - xi * c.y);
  q[base + 1] = bf16_bits(xr * c.y + xi * c.x);
}

__global__ void k_rope_k(unsigned short* __restrict__ ckv, const float2* __restrict__ cs) {
  int idx = blockIdx.x * 256 + threadIdx.x;  // BS*32
  int i = idx & 31;
  int bs = idx >> 5;
  int s = bs & 2047;
  size_t base = (size_t)bs * 576 + 512 + 2 * i;
  float xr = bf16_to_f(ckv[base]);
  float xi = bf16_to_f(ckv[base + 1]);
  float2 c = cs[(s << 5) + i];
  ckv[base]     = bf16_bits(xr * c.x - xi * c.y);
  ckv[base + 1] = bf16_bits(xr * c.y + xi * c.x);
}

// ---------------- GEMM: C[M][N] = A[M][K](lda) @ Wt[N][K]^T + bias ----------------
// 128x128 tile, BK=64, 256 threads (4 waves 2x2).
// Staging: global_load_lds dwordx4; LDS is linear [128][64] u16, but the global
// SOURCE column chunk is pre-swizzled: slot s of row r holds chunk s ^ (r&7).
// Fragment ds_read applies the same XOR -> 2-way banks (free), no VALU staging.

template <typename OutT>
__global__ __launch_bounds__(256, 2) void k_gemm(const unsigned short* __restrict__ A, int lda,
                                                 const unsigned short* __restrict__ Wt,
                                                 const float* __restrict__ bias,
                                                 OutT* __restrict__ C, int M, int N, int K) {
  __shared__ unsigned short lA[128][64];
  __shared__ unsigned short lB[128][64];
  int m0 = blockIdx.x * 128, n0 = blockIdx.y * 128;
  int t = threadIdx.x;
  int lane = t & 63, wid = t >> 6;
  int g = lane >> 4, col = lane & 15;
  int wr = wid >> 1, wc = wid & 1;
  int srow = lane >> 3;                 // 0..7 within wave chunk
  int schunk = (lane & 7) ^ srow;       // inverse-swizzled source chunk
  f32x4 acc[4][4] = {};

  for (int kt = 0; kt < K; kt += 64) {
#pragma unroll
    for (int i = 0; i < 4; ++i) {
      int rowb = 32 * wid + 8 * i;      // wave-uniform LDS row base
      int row = rowb + srow;
      GLOAD_LDS16(&A[(size_t)(m0 + row) * lda + kt + 8 * schunk], &lA[rowb][0]);
      GLOAD_LDS16(&Wt[(size_t)(n0 + row) * K + kt + 8 * schunk], &lB[rowb][0]);
    }
    __syncthreads();
#pragma unroll
    for (int kk = 0; kk < 64; kk += 32) {
      int ch = (kk >> 3) + g;
      int sl = 8 * (ch ^ (col & 7));
      short8 a[4], b[4];
#pragma unroll
      for (int mf = 0; mf < 4; ++mf)
        a[mf] = *reinterpret_cast<const short8*>(&lA[64 * wr + 16 * mf + col][sl]);
#pragma unroll
      for (int nf = 0; nf < 4; ++nf)
        b[nf] = *reinterpret_cast<const short8*>(&lB[64 * wc + 16 * nf + col][sl]);
#pragma unroll
      for (int mf = 0; mf < 4; ++mf)
#pragma unroll
        for (int nf = 0; nf < 4; ++nf)
          acc[mf][nf] = __builtin_amdgcn_mfma_f32_16x16x32_bf16(a[mf], b[nf], acc[mf][nf], 0, 0, 0);
    }
    __syncthreads();
  }

#pragma unroll
  for (int mf = 0; mf < 4; ++mf) {
#pragma unroll
    for (int nf = 0; nf < 4; ++nf) {
      int n = n0 + 64 * wc + 16 * nf + col;
      if (n >= N) continue;
      float bv = bias[n];
#pragma unroll
      for (int r = 0; r < 4; ++r) {
        int m = m0 + 64 * wr + 16 * mf + 4 * g + r;
        float v = acc[mf][nf][r] + bv;
        if constexpr (sizeof(OutT) == 4)
          C[(size_t)m * N + n] = v;
        else
          C[(size_t)m * N + n] = bf16_bits(v);
      }
    }
  }
}

// ---------------- flash attention ----------------
// grid = B*H*(S/128) = 512 blocks, 512 threads = 8 waves; wave w owns q-rows [q0+16w, +16).
// KV-tile 64 shared by all 8 waves. V^T staged with XOR chunk swizzle:
//   element V[k][dv] lives at lV[dv][ ((k>>3) ^ ((dv>>3)&7))*8 + (k&7) ]

__global__ __launch_bounds__(512, 4) void k_attn(const unsigned short* __restrict__ q,
                                                 const unsigned short* __restrict__ ckv,
                                                 const unsigned short* __restrict__ kv,
                                                 unsigned short* __restrict__ out) {
  __shared__ unsigned short lK[64][200];    // 64 kv-rows x 192 dims (+8 pad)
  __shared__ unsigned short lV[128][72];    // V^T swizzled: 128 dv x 64 kv (+8 pad)
  __shared__ unsigned short lP[8][16][72];  // per-wave P 16x64 (+8 pad), wave-private
  int bx = blockIdx.x;
  int qt = bx & 15, h = (bx >> 4) & 15, b = bx >> 8;
  int t = threadIdx.x, lane = t & 63, w = t >> 6;
  int g = lane >> 4, col = lane & 15;
  int q0 = qt * 128;
  const float scale = 0.08838834764831845f;  // 1/sqrt(128)

  short8 qf[6];
  {
    int srow = b * 2048 + q0 + 16 * w + col;
    size_t base = ((size_t)srow * 16 + h) * 192 + 8 * g;
#pragma unroll
    for (int j = 0; j < 6; ++j)
      qf[j] = *reinterpret_cast<const short8*>(&q[base + 32 * j]);
  }

  f32x4 o[8] = {};
  float mrow[4] = {-1e30f, -1e30f, -1e30f, -1e30f};
  float lrow[4] = {0.f, 0.f, 0.f, 0.f};

  for (int k0 = 0; k0 < 2048; k0 += 64) {
    __syncthreads();  // prior PV reads done before overwrite
    // stage K: 64 rows x 24 chunks of 8 bf16 (nope from kv, rope from ckv) = 1536 chunks
#pragma unroll
    for (int it = 0; it < 3; ++it) {
      int c = t + 512 * it;
      int row = c / 24, cc = c % 24;
      int s = b * 2048 + k0 + row;
      const unsigned short* src;
      if (cc < 16) src = &kv[((size_t)s * 16 + h) * 256 + cc * 8];
      else         src = &ckv[(size_t)s * 576 + 512 + (cc - 16) * 8];
      *reinterpret_cast<short8*>(&lK[row][cc * 8]) = *reinterpret_cast<const short8*>(src);
    }
    // stage V transposed, swizzled: 64 rows x 16 chunks = 1024
#pragma unroll
    for (int it = 0; it < 2; ++it) {
      int c = t + 512 * it;
      int kr = c >> 4, dv0 = (c & 15) * 8;
      int s = b * 2048 + k0 + kr;
      short8 v = *reinterpret_cast<const short8*>(&kv[((size_t)s * 16 + h) * 256 + 128 + dv0]);
      int swz = (((kr >> 3) ^ ((dv0 >> 3) & 7)) << 3) + (kr & 7);
#pragma unroll
      for (int j = 0; j < 8; ++j) lV[dv0 + j][swz] = (unsigned short)v[j];
    }
    __syncthreads();

    // S = Q K^T for this wave's 16 rows x 64 cols
    f32x4 sf[4];
#pragma unroll
    for (int c = 0; c < 4; ++c) {
      f32x4 acc = {};
#pragma unroll
      for (int j = 0; j < 6; ++j) {
        short8 bfr = *reinterpret_cast<const short8*>(&lK[16 * c + col][32 * j + 8 * g]);
        acc = __builtin_amdgcn_mfma_f32_16x16x32_bf16(qf[j], bfr, acc, 0, 0, 0);
      }
      sf[c] = acc;
    }

    // online softmax; row r of this lane = q0+16w+4g+r
#pragma unroll
    for (int r = 0; r < 4; ++r) {
      float tm = -1e30f;
#pragma unroll
      for (int c = 0; c < 4; ++c) { sf[c][r] *= scale; tm = fmaxf(tm, sf[c][r]); }
#pragma unroll
      for (int off = 8; off; off >>= 1) tm = fmaxf(tm, __shfl_xor(tm, off, 64));
      float mn = fmaxf(mrow[r], tm);
      float rs = __expf(mrow[r] - mn);
      mrow[r] = mn;
      float ps = 0.f;
#pragma unroll
      for (int c = 0; c < 4; ++c) { float p = __expf(sf[c][r] - mn); sf[c][r] = p; ps += p; }
#pragma unroll
      for (int off = 8; off; off >>= 1) ps += __shfl_xor(ps, off, 64);
      lrow[r] = lrow[r] * rs + ps;
#pragma unroll
      for (int n = 0; n < 8; ++n) o[n][r] *= rs;
    }

    // P -> wave-private LDS (bf16); same-wave DS ops are in-order, no block barrier.
#pragma unroll
    for (int c = 0; c < 4; ++c)
#pragma unroll
      for (int r = 0; r < 4; ++r)
        lP[w][4 * g + r][16 * c + col] = bf16_bits(sf[c][r]);
#pragma unroll
    for (int kk = 0; kk < 64; kk += 32) {
      short8 pa = *reinterpret_cast<const short8*>(&lP[w][col][kk + 8 * g]);
#pragma unroll
      for (int n = 0; n < 8; ++n) {
        int dv = 16 * n + col;
        int phys = ((((kk + 8 * g) >> 3) ^ ((dv >> 3) & 7)) << 3);
        short8 bv = *reinterpret_cast<const short8*>(&lV[dv][phys]);
        o[n] = __builtin_amdgcn_mfma_f32_16x16x32_bf16(pa, bv, o[n], 0, 0, 0);
      }
    }
  }

  // epilogue: normalize, write (B,S,H*128) bf16
#pragma unroll
  for (int r = 0; r < 4; ++r) {
    float inv = 1.0f / lrow[r];
    int srow = b * 2048 + q0 + 16 * w + 4 * g + r;
    size_t base = (size_t)srow * 2048 + h * 128;
#pragma unroll
    for (int n = 0; n < 8; ++n)
      out[base + 16 * n + col] = bf16_bits(o[n][r] * inv);
  }
}

// ---------------- host ----------------

extern "C" void kernel_launch(void* const* d_in, const int* in_sizes, int n_in,
                              void* d_out, int out_size, void* d_ws, size_t ws_size,
                              hipStream_t stream) {
  const float* x       = (const float*)d_in[0];
  const float* wq_a_w  = (const float*)d_in[1];
  const float* wq_a_b  = (const float*)d_in[2];
  const float* wq_b_w  = (const float*)d_in[3];
  const float* wq_b_b  = (const float*)d_in[4];
  const float* wkv_a_w = (const float*)d_in[5];
  const float* wkv_a_b = (const float*)d_in[6];
  const float* wkv_b_w = (const float*)d_in[7];
  const float* wkv_b_b = (const float*)d_in[8];
  const float* wo_w    = (const float*)d_in[9];
  const float* wo_b    = (const float*)d_in[10];
  float* out = (float*)d_out;

  const int BS = 4096;  // B*S = 2*2048
  char* p = (char*)d_ws;
  auto alloc = [&](size_t bytes) { char* r = p; p += (bytes + 255) & ~(size_t)255; return r; };
  unsigned short* xb    = (unsigned short*)alloc((size_t)BS * 2048 * 2);
  unsigned short* wqat  = (unsigned short*)alloc((size_t)512 * 2048 * 2);
  unsigned short* wqbt  = (unsigned short*)alloc((size_t)3072 * 512 * 2);
  unsigned short* wkvat = (unsigned short*)alloc((size_t)640 * 2048 * 2);  // padded 576->640
  unsigned short* wkvbt = (unsigned short*)alloc((size_t)4096 * 512 * 2);
  unsigned short* wot   = (unsigned short*)alloc((size_t)2048 * 2048 * 2);
  unsigned short* qa    = (unsigned short*)alloc((size_t)BS * 512 * 2);
  unsigned short* qbuf  = (unsigned short*)alloc((size_t)BS * 3072 * 2);
  unsigned short* ckv   = (unsigned short*)alloc((size_t)BS * 576 * 2);
  unsigned short* kvbuf = (unsigned short*)alloc((size_t)BS * 4096 * 2);
  unsigned short* attno = (unsigned short*)alloc((size_t)BS * 2048 * 2);
  float2* cs            = (float2*)alloc((size_t)2048 * 32 * sizeof(float2));

  k_f32_to_bf16<<<BS * 2048 / 4 / 256, 256, 0, stream>>>(x, xb, BS * 2048 / 4);
  k_transpose_bf16<<<dim3(2048 / 32, 512 / 32), 256, 0, stream>>>(wq_a_w, wqat, 2048, 512);
  k_transpose_bf16<<<dim3(512 / 32, 3072 / 32), 256, 0, stream>>>(wq_b_w, wqbt, 512, 3072);
  k_transpose_bf16<<<dim3(2048 / 32, 576 / 32), 256, 0, stream>>>(wkv_a_w, wkvat, 2048, 576);
  k_transpose_bf16<<<dim3(512 / 32, 4096 / 32), 256, 0, stream>>>(wkv_b_w, wkvbt, 512, 4096);
  k_transpose_bf16<<<dim3(2048 / 32, 2048 / 32), 256, 0, stream>>>(wo_w, wot, 2048, 2048);
  k_rope_table<<<2048 * 32 / 256, 256, 0, stream>>>(cs);

  // GEMM1: q_a = x @ wq_a + b
  k_gemm<unsigned short><<<dim3(BS / 128, 512 / 128), 256, 0, stream>>>(
      xb, 2048, wqat, wq_a_b, qa, BS, 512, 2048);
  // GEMM2: q = q_a @ wq_b + b
  k_gemm<unsigned short><<<dim3(BS / 128, 3072 / 128), 256, 0, stream>>>(
      qa, 512, wqbt, wq_b_b, qbuf, BS, 3072, 512);
  // GEMM3: ckv = x @ wkv_a + b
  k_gemm<unsigned short><<<dim3(BS / 128, (576 + 127) / 128), 256, 0, stream>>>(
      xb, 2048, wkvat, wkv_a_b, ckv, BS, 576, 2048);
  // RoPE in place
  k_rope_q<<<BS * 16 * 32 / 256, 256, 0, stream>>>(qbuf, cs);
  k_rope_k<<<BS * 32 / 256, 256, 0, stream>>>(ckv, cs);
  // GEMM4: kv = compressed_kv @ wkv_b + b
  k_gemm<unsigned short><<<dim3(BS / 128, 4096 / 128), 256, 0, stream>>>(
      ckv, 576, wkvbt, wkv_b_b, kvbuf, BS, 4096, 512);
  // attention: 512 blocks x 512 threads
  k_attn<<<2 * 16 * 16, 512, 0, stream>>>(qbuf, ckv, kvbuf, attno);
  // GEMM5: final projection, fp32 out
  k_gemm<float><<<dim3(BS / 128, 2048 / 128), 256, 0, stream>>>(
      attno, 2048, wot, wo_b, out, BS, 2048, 2048);
}